// Round 23
// baseline (127.287 us; speedup 1.0000x reference)
//
#include <hip/hip_runtime.h>
#include <math.h>

#define T_LEN 4096
#define M_LEN 2048   // complex length after real-packing
#define V_DIM 32
#define B_DIM 128
#define NTHREADS 256
#define NWAVES 4
#define NSERIES 4096          // B_DIM * V_DIM
#define FS NSERIES            // feats stride: feature-major [f][sid]

// LDS bank swizzle on float2 index: fold addr bits 4-6 into 1-3 AND bits 7-10
// into 1-4. Kills the 16-way magnitude-gather conflict (fpos puts k0..k5 at
// addr bits 5-10, leaving bank bits constant under the old swizzle).
// Bit 0 untouched; XOR terms depend only on bits>=4 -> even/odd f2 pairs stay
// adjacent (b128-safe, 16B aligned); bijective; range-preserving.
__device__ __forceinline__ int SW(int i) {
    return i ^ (((i >> 4) & 7) << 1) ^ (((i >> 7) & 15) << 1);
}

// storage position of frequency k after DIF [radix-4 x5, radix-2] (digit reversal)
__device__ __forceinline__ int fpos(int k) {
    return ((k & 3) << 9) | (((k >> 2) & 3) << 7) | (((k >> 4) & 3) << 5)
         | (((k >> 6) & 3) << 3) | (((k >> 8) & 3) << 1) | ((k >> 10) & 1);
}

// insert m into descending triple (a0 >= a1 >= a2)
__device__ __forceinline__ void ins3(float& a0, float& a1, float& a2, float m) {
    if (m > a0) { a2 = a1; a1 = a0; a0 = m; }
    else if (m > a1) { a2 = a1; a1 = m; }
    else if (m > a2) { a2 = m; }
}

// scr float regions (single series, 4 waves)
#define SCR_A_PART 0     // 4 waves x 3 [sum,mn,mx]
#define SCR_A_FIN  12    // 3
#define SCR_B_PART 16    // 4 waves x 4 lanes x 10
#define SCR_B_FIN  176   // 10
#define SCR_C_PART 186   // 4 waves x 3
#define SCR_SIZE   200

// one radix-4 DIF butterfly at (base, quarter q) with twiddles W^j, W^2j, W^3j
__device__ __forceinline__ void bfly4(float2* Z, int base, int q,
                                      float sn, float cs, float c2, float s2,
                                      float c3, float s3) {
    const int p0 = SW(base), p1 = SW(base + q);
    const int p2i = SW(base + 2 * q), p3 = SW(base + 3 * q);
    float2 a = Z[p0], bb = Z[p1], c = Z[p2i], d = Z[p3];
    float t0r = a.x + c.x,  t0i = a.y + c.y;
    float t1r = a.x - c.x,  t1i = a.y - c.y;
    float t2r = bb.x + d.x, t2i = bb.y + d.y;
    float t3r = bb.x - d.x, t3i = bb.y - d.y;
    float y1r = t1r + t3i, y1i = t1i - t3r;
    float y2r = t0r - t2r, y2i = t0i - t2i;
    float y3r = t1r - t3i, y3i = t1i + t3r;
    Z[p0]  = make_float2(t0r + t2r, t0i + t2i);
    Z[p1]  = make_float2(y1r * cs - y1i * sn, y1r * sn + y1i * cs);
    Z[p2i] = make_float2(y2r * c2 - y2i * s2, y2r * s2 + y2i * c2);
    Z[p3]  = make_float2(y3r * c3 - y3i * s3, y3r * s3 + y3i * c3);
}

// radix-4 DIF stage, in place, swizzled addressing. W = e^{-2pi i/2048}.
// For ST>=1 the thread's two butterflies share j (256 % q == 0) -> one sincos.
template <int ST>
__device__ __forceinline__ void fft_stage(float2* Z, int tid) {
    constexpr int lq = 9 - 2 * ST;           // log2(quarter)
    constexpr int q  = 1 << lq;
    const float scale = -3.06796158e-3f * (float)(1 << (2 * ST)); // -2pi/2048 * 4^ST
    if constexpr (ST == 0) {
        #pragma unroll
        for (int i = 0; i < 2; i++) {
            const int w = tid + (i << 8);
            const int g = w >> lq;
            const int j = w & (q - 1);
            float sn, cs;
            __sincosf(scale * (float)j, &sn, &cs);
            const float c2 = cs * cs - sn * sn, s2 = 2.f * cs * sn;
            const float c3 = c2 * cs - s2 * sn, s3 = c2 * sn + s2 * cs;
            bfly4(Z, (g << (lq + 2)) + j, q, sn, cs, c2, s2, c3, s3);
        }
    } else {
        const int j = tid & (q - 1);
        float sn, cs;
        __sincosf(scale * (float)j, &sn, &cs);
        const float c2 = cs * cs - sn * sn, s2 = 2.f * cs * sn;
        const float c3 = c2 * cs - s2 * sn, s3 = c2 * sn + s2 * cs;
        #pragma unroll
        for (int i = 0; i < 2; i++) {
            const int g = (tid + (i << 8)) >> lq;
            bfly4(Z, (g << (lq + 2)) + j, q, sn, cs, c2, s2, c3, s3);
        }
    }
}

// post-radix2 value at logical position p (radix-2 stage fused: pair add/sub)
__device__ __forceinline__ float2 rdpost(const float2* Z, int p) {
    int e = p & ~1;
    float4 v = *reinterpret_cast<const float4*>(&Z[SW(e)]);
    return (p & 1) ? make_float2(v.x - v.z, v.y - v.w)
                   : make_float2(v.x + v.z, v.y + v.w);
}

__global__ __launch_bounds__(NTHREADS, 8)   // 8 blocks/CU: 32 waves (session-best config)
void ts_feat_kernel(const float* __restrict__ x, float* __restrict__ feats) {
    __shared__ __align__(16) float data[T_LEN];      // 16 KB swizzled packed-complex
    __shared__ float scr[SCR_SIZE];
    float2* const Z = reinterpret_cast<float2*>(&data[0]);

    const int tid = threadIdx.x;
    // XCD swizzle: all 32 v-blocks of batch b land on XCD b&7; bijective over 4096.
    const int bid = blockIdx.x;            // 0..4095
    const int xcd = bid & 7;
    const int idx = bid >> 3;              // 0..511
    const int b   = xcd + ((idx >> 5) << 3);    // batch 0..127
    const int v   = idx & 31;
    const int sid = b * V_DIM + v;

    const float* __restrict__ px = x + (size_t)b * T_LEN * V_DIM + v;

    // ---------- sweep 1: 16 scalar loads -> regs; sum/min/max; LDS store ----------
    float xr[16];
    #pragma unroll
    for (int u = 0; u < 16; u++) {
        xr[u] = px[(size_t)(16 * tid + u) * V_DIM];
    }
    float s = 0.f, mn = 3.4e38f, mx = -3.4e38f;
    #pragma unroll
    for (int u = 0; u < 16; u++) {
        s += xr[u]; mn = fminf(mn, xr[u]); mx = fmaxf(mx, xr[u]);
    }
    const int fb2 = tid * 8;               // first owned float2 index
    #pragma unroll
    for (int u4 = 0; u4 < 4; u4++) {
        float4 q = make_float4(xr[4 * u4], xr[4 * u4 + 1], xr[4 * u4 + 2], xr[4 * u4 + 3]);
        *reinterpret_cast<float4*>(&Z[SW(fb2 + 2 * u4)]) = q;
    }
    #pragma unroll
    for (int o = 32; o > 0; o >>= 1) {
        s += __shfl_down(s, o);
        mn = fminf(mn, __shfl_down(mn, o));
        mx = fmaxf(mx, __shfl_down(mx, o));
    }
    const int lane = tid & 63, wv = tid >> 6;
    if (lane == 0) {
        scr[SCR_A_PART + wv * 3 + 0] = s;
        scr[SCR_A_PART + wv * 3 + 1] = mn;
        scr[SCR_A_PART + wv * 3 + 2] = mx;
    }
    __syncthreads();                                     // sync 1
    if (tid < 3) {
        float r = scr[SCR_A_PART + tid];
        #pragma unroll
        for (int w = 1; w < NWAVES; w++) {
            float vv = scr[SCR_A_PART + w * 3 + tid];
            r = (tid == 0) ? (r + vv) : ((tid == 1) ? fminf(r, vv) : fmaxf(r, vv));
        }
        scr[SCR_A_FIN + tid] = r;
    }
    __syncthreads();                                     // sync 2
    const float m = scr[SCR_A_FIN + 0] * (1.f / T_LEN);

    // ---------- sweep 2: fused moments/slope/ACF from REGISTERS ----------
    {
        float q2 = 0.f, q3 = 0.f, q4 = 0.f, qt = 0.f;
        float l1 = 0.f, l2 = 0.f, l3 = 0.f, l4 = 0.f, l5 = 0.f, l6 = 0.f;
        float p1v, p2v, p3v, p4v, p5v, p6v;
        if (tid > 0) {                     // boundary x[16t-6..16t-1] from LDS
            float2 tv = Z[SW(fb2 - 3)];
            float4 tq = *reinterpret_cast<const float4*>(&Z[SW(fb2 - 2)]);
            p6v = tv.x - m; p5v = tv.y - m;
            p4v = tq.x - m; p3v = tq.y - m; p2v = tq.z - m; p1v = tq.w - m;
        } else {
            p1v = p2v = p3v = p4v = p5v = p6v = 0.f;     // reference zero-pads
        }
        const float tf0 = (float)(tid * 16) - 2047.5f;
        #pragma unroll
        for (int u = 0; u < 16; u++) {
            float c = xr[u] - m;
            float cc = c * c;
            q2 += cc; q3 += cc * c; q4 += cc * cc;
            qt += c * (tf0 + (float)u);
            l1 += p1v * c; l2 += p2v * c; l3 += p3v * c;
            l4 += p4v * c; l5 += p5v * c; l6 += p6v * c;
            p6v = p5v; p5v = p4v; p4v = p3v; p3v = p2v; p2v = p1v; p1v = c;
        }
        #pragma unroll
        for (int o = 32; o >= 4; o >>= 1) {
            q2 += __shfl_down(q2, o); q3 += __shfl_down(q3, o);
            q4 += __shfl_down(q4, o); qt += __shfl_down(qt, o);
            l1 += __shfl_down(l1, o); l2 += __shfl_down(l2, o);
            l3 += __shfl_down(l3, o); l4 += __shfl_down(l4, o);
            l5 += __shfl_down(l5, o); l6 += __shfl_down(l6, o);
        }
        if (lane < 4) {
            float* part = &scr[SCR_B_PART + wv * 40 + lane * 10];
            part[0] = q2; part[1] = q3; part[2] = q4; part[3] = qt;
            part[4] = l1; part[5] = l2; part[6] = l3;
            part[7] = l4; part[8] = l5; part[9] = l6;
        }
    }
    __syncthreads();                                     // sync 3

    // ---------- B finalize overlapped with FFT stage 0 ----------
    if (tid < 10) {
        float acc = 0.f;
        #pragma unroll
        for (int e = 0; e < 16; e++) acc += scr[SCR_B_PART + e * 10 + tid];
        scr[SCR_B_FIN + tid] = acc;
    }
    fft_stage<0>(Z, tid);
    __syncthreads();                                     // sync 4

    // feats base features by tid 0 (feature-major), overlap FFT stage 1
    if (tid == 0) {
        const float* A = &scr[SCR_B_FIN];
        float c2 = A[0], c3 = A[1], c4 = A[2], ct = A[3];
        float var = c2 * (1.f / T_LEN);
        float sd  = sqrtf(var + 1e-8f);
        float i3  = 1.f / (sd * sd * sd);
        float dn  = c2 + 1e-8f;
        float* fp = feats + sid;
        fp[0 * FS] = m; fp[1 * FS] = sd;
        fp[2 * FS] = c3 * (1.f / T_LEN) * i3;
        fp[3 * FS] = c4 * (1.f / T_LEN) * i3 / sd;
        fp[4 * FS] = scr[SCR_A_FIN + 1]; fp[5 * FS] = scr[SCR_A_FIN + 2];
        fp[6 * FS] = ct / 5726622720.f;                  // sum(tc^2) = T(T^2-1)/12
        fp[10 * FS] = A[4] / dn; fp[11 * FS] = A[5] / dn; fp[12 * FS] = A[6] / dn;
        fp[13 * FS] = A[7] / dn; fp[14 * FS] = A[8] / dn; fp[15 * FS] = A[9] / dn;
    }
    fft_stage<1>(Z, tid);
    __syncthreads();                                     // sync 5
    fft_stage<2>(Z, tid);
    __syncthreads();                                     // sync 6
    fft_stage<3>(Z, tid);
    __syncthreads();                                     // sync 7
    fft_stage<4>(Z, tid);
    __syncthreads();                                     // sync 8

    // ---------- magnitudes: conjugate pair once; mag^2, sqrt deferred ----------
    // X_k = (Er+u, Ei+v), X_{2048-k} = (Er-u, v-Ei)
    const float inv_T = 1.f / (float)T_LEN;
    float a0 = -1.f, a1 = -1.f, a2 = -1.f;               // top-3 of |X|^2
    #pragma unroll
    for (int i = 0; i < 4; i++) {
        int k  = 1 + tid + (i << 8);                     // 1..1024
        int pa = fpos(k);
        int pb = fpos(M_LEN - k);
        float ang = (float)k * (-3.14159265358979f / (float)M_LEN);
        float sn, cs; __sincosf(ang, &sn, &cs);
        float2 Za = rdpost(Z, pa), Zb = rdpost(Z, pb);
        float Er = 0.5f * (Za.x + Zb.x), Ei = 0.5f * (Za.y - Zb.y);
        float Or = 0.5f * (Za.y + Zb.y), Oi = 0.5f * (Zb.x - Za.x);
        float u = cs * Or - sn * Oi, vv = cs * Oi + sn * Or;
        float Xr = Er + u, Xi = Ei + vv;
        ins3(a0, a1, a2, Xr * Xr + Xi * Xi);
        if (k != 1024) {
            float Yr = Er - u, Yi = vv - Ei;
            ins3(a0, a1, a2, Yr * Yr + Yi * Yi);
        }
    }
    if (tid == 0) {                                      // Nyquist k=2048
        float2 Z0 = rdpost(Z, 0);
        float d = Z0.x - Z0.y;
        ins3(a0, a1, a2, d * d);
    }
    #pragma unroll
    for (int o = 32; o > 0; o >>= 1) {
        float u0 = __shfl_down(a0, o), u1 = __shfl_down(a1, o), u2 = __shfl_down(a2, o);
        ins3(a0, a1, a2, u0); ins3(a0, a1, a2, u1); ins3(a0, a1, a2, u2);
    }
    if (lane == 0) {
        scr[SCR_C_PART + wv * 3 + 0] = a0;
        scr[SCR_C_PART + wv * 3 + 1] = a1;
        scr[SCR_C_PART + wv * 3 + 2] = a2;
    }
    __syncthreads();                                     // sync 9
    if (tid == 0) {
        float t0 = scr[SCR_C_PART], t1 = scr[SCR_C_PART + 1], t2 = scr[SCR_C_PART + 2];
        #pragma unroll
        for (int w = 1; w < NWAVES; w++) {
            ins3(t0, t1, t2, scr[SCR_C_PART + w * 3 + 0]);
            ins3(t0, t1, t2, scr[SCR_C_PART + w * 3 + 1]);
            ins3(t0, t1, t2, scr[SCR_C_PART + w * 3 + 2]);
        }
        float* fp = feats + sid;
        fp[7 * FS] = sqrtf(t0) * inv_T;
        fp[8 * FS] = sqrtf(t1) * inv_T;
        fp[9 * FS] = sqrtf(t2) * inv_T;
    }
}

// One 32-lane group per (b, f): coalesced 128-B read + shuffle reduce.
__global__ __launch_bounds__(256)
void ts_reduce_kernel(const float* __restrict__ feats, float* __restrict__ out) {
    const int tid = threadIdx.x;
    const int lane = tid & 63;
    const int wid = blockIdx.x * 4 + (tid >> 6);      // global wave 0..1023
    const int pairidx = wid * 2 + (lane >> 5);        // (b,f) pair 0..2047
    const int b = pairidx >> 4, f = pairidx & 15;
    const int v = lane & 31;
    float val = feats[f * FS + b * V_DIM + v];
    float s = val;
    #pragma unroll
    for (int o = 16; o > 0; o >>= 1) s += __shfl_xor(s, o);
    float m = s * (1.f / V_DIM);
    float d = val - m;
    float q = d * d;
    #pragma unroll
    for (int o = 16; o > 0; o >>= 1) q += __shfl_xor(q, o);
    float sd = sqrtf(q * (1.f / V_DIM));
    if (v == 0) {
        out[b * 32 + f]      = fminf(fmaxf(m,  -5.f), 5.f);
        out[b * 32 + 16 + f] = fminf(fmaxf(sd, -5.f), 5.f);
    }
}

extern "C" void kernel_launch(void* const* d_in, const int* in_sizes, int n_in,
                              void* d_out, int out_size, void* d_ws, size_t ws_size,
                              hipStream_t stream) {
    const float* x = (const float*)d_in[0];
    float* out = (float*)d_out;
    float* feats = (float*)d_ws;   // feature-major [16][4096] = 256 KB

    hipLaunchKernelGGL(ts_feat_kernel, dim3(NSERIES), dim3(NTHREADS), 0, stream,
                       x, feats);
    hipLaunchKernelGGL(ts_reduce_kernel, dim3(256), dim3(256), 0, stream,
                       feats, out);
}

// Round 24
// 127.051 us; speedup vs baseline: 1.0019x; 1.0019x over previous
//
#include <hip/hip_runtime.h>
#include <math.h>

#define T_LEN 4096
#define M_LEN 2048   // complex length after real-packing
#define V_DIM 32
#define B_DIM 128
#define NTHREADS 256
#define NWAVES 4
#define NSERIES 4096          // B_DIM * V_DIM
#define FS NSERIES            // feats stride: feature-major [f][sid]

// LDS bank swizzle on float2 index: fold addr bits 4-6 into 1-3 AND bits 7-10
// into 1-4 (kills the 16-way magnitude-gather conflict; r23: 5.0e6 -> 1.7e6).
// Bit 0 untouched; XOR terms depend only on bits>=4 -> even/odd f2 pairs stay
// adjacent (b128-safe, 16B aligned); bijective; range-preserving.
__device__ __forceinline__ int SW(int i) {
    return i ^ (((i >> 4) & 7) << 1) ^ (((i >> 7) & 15) << 1);
}

// storage position of frequency k after DIF [radix-4 x5, radix-2] (digit reversal)
__device__ __forceinline__ int fpos(int k) {
    return ((k & 3) << 9) | (((k >> 2) & 3) << 7) | (((k >> 4) & 3) << 5)
         | (((k >> 6) & 3) << 3) | (((k >> 8) & 3) << 1) | ((k >> 10) & 1);
}

// insert m into descending triple (a0 >= a1 >= a2)
__device__ __forceinline__ void ins3(float& a0, float& a1, float& a2, float m) {
    if (m > a0) { a2 = a1; a1 = a0; a0 = m; }
    else if (m > a1) { a2 = a1; a1 = m; }
    else if (m > a2) { a2 = m; }
}

// scr float regions (single series, 4 waves)
#define SCR_A_PART 0     // 4 waves x 3 [sum,mn,mx]
#define SCR_A_FIN  12    // 3
#define SCR_B_PART 16    // 4 waves x 4 lanes x 10
#define SCR_B_FIN  176   // 10
#define SCR_C_PART 186   // 4 waves x 3
#define SCR_SIZE   200

// one radix-4 DIF butterfly at (base, quarter q) with twiddles W^j, W^2j, W^3j
__device__ __forceinline__ void bfly4(float2* Z, int base, int q,
                                      float sn, float cs, float c2, float s2,
                                      float c3, float s3) {
    const int p0 = SW(base), p1 = SW(base + q);
    const int p2i = SW(base + 2 * q), p3 = SW(base + 3 * q);
    float2 a = Z[p0], bb = Z[p1], c = Z[p2i], d = Z[p3];
    float t0r = a.x + c.x,  t0i = a.y + c.y;
    float t1r = a.x - c.x,  t1i = a.y - c.y;
    float t2r = bb.x + d.x, t2i = bb.y + d.y;
    float t3r = bb.x - d.x, t3i = bb.y - d.y;
    float y1r = t1r + t3i, y1i = t1i - t3r;
    float y2r = t0r - t2r, y2i = t0i - t2i;
    float y3r = t1r - t3i, y3i = t1i + t3r;
    Z[p0]  = make_float2(t0r + t2r, t0i + t2i);
    Z[p1]  = make_float2(y1r * cs - y1i * sn, y1r * sn + y1i * cs);
    Z[p2i] = make_float2(y2r * c2 - y2i * s2, y2r * s2 + y2i * c2);
    Z[p3]  = make_float2(y3r * c3 - y3i * s3, y3r * s3 + y3i * c3);
}

// radix-4 DIF stage, in place, swizzled addressing. W = e^{-2pi i/2048}.
// For ST>=1 the thread's two butterflies share j (256 % q == 0) -> one sincos.
template <int ST>
__device__ __forceinline__ void fft_stage(float2* Z, int tid) {
    constexpr int lq = 9 - 2 * ST;           // log2(quarter)
    constexpr int q  = 1 << lq;
    const float scale = -3.06796158e-3f * (float)(1 << (2 * ST)); // -2pi/2048 * 4^ST
    if constexpr (ST == 0) {
        #pragma unroll
        for (int i = 0; i < 2; i++) {
            const int w = tid + (i << 8);
            const int g = w >> lq;
            const int j = w & (q - 1);
            float sn, cs;
            __sincosf(scale * (float)j, &sn, &cs);
            const float c2 = cs * cs - sn * sn, s2 = 2.f * cs * sn;
            const float c3 = c2 * cs - s2 * sn, s3 = c2 * sn + s2 * cs;
            bfly4(Z, (g << (lq + 2)) + j, q, sn, cs, c2, s2, c3, s3);
        }
    } else {
        const int j = tid & (q - 1);
        float sn, cs;
        __sincosf(scale * (float)j, &sn, &cs);
        const float c2 = cs * cs - sn * sn, s2 = 2.f * cs * sn;
        const float c3 = c2 * cs - s2 * sn, s3 = c2 * sn + s2 * cs;
        #pragma unroll
        for (int i = 0; i < 2; i++) {
            const int g = (tid + (i << 8)) >> lq;
            bfly4(Z, (g << (lq + 2)) + j, q, sn, cs, c2, s2, c3, s3);
        }
    }
}

// post-radix2 value at logical position p (radix-2 stage fused: pair add/sub)
__device__ __forceinline__ float2 rdpost(const float2* Z, int p) {
    int e = p & ~1;
    float4 v = *reinterpret_cast<const float4*>(&Z[SW(e)]);
    return (p & 1) ? make_float2(v.x - v.z, v.y - v.w)
                   : make_float2(v.x + v.z, v.y + v.w);
}

__global__ __launch_bounds__(NTHREADS, 8)   // 8 blocks/CU: 32 waves (session-best config)
void ts_feat_kernel(const float* __restrict__ x, float* __restrict__ feats) {
    __shared__ __align__(16) float data[T_LEN];      // 16 KB swizzled packed-complex
    __shared__ float scr[SCR_SIZE];
    float2* const Z = reinterpret_cast<float2*>(&data[0]);

    const int tid = threadIdx.x;
    // XCD swizzle: all 32 v-blocks of batch b land on XCD b&7; bijective over 4096.
    const int bid = blockIdx.x;            // 0..4095
    const int xcd = bid & 7;
    const int idx = bid >> 3;              // 0..511
    const int b   = xcd + ((idx >> 5) << 3);    // batch 0..127
    const int v   = idx & 31;
    const int sid = b * V_DIM + v;

    const float* __restrict__ px = x + (size_t)b * T_LEN * V_DIM + v;

    // ---------- sweep 1: 16 scalar loads -> regs; sum/min/max; LDS store ----------
    float xr[16];
    #pragma unroll
    for (int u = 0; u < 16; u++) {
        xr[u] = px[(size_t)(16 * tid + u) * V_DIM];
    }
    float s = 0.f, mn = 3.4e38f, mx = -3.4e38f;
    #pragma unroll
    for (int u = 0; u < 16; u++) {
        s += xr[u]; mn = fminf(mn, xr[u]); mx = fmaxf(mx, xr[u]);
    }
    const int fb2 = tid * 8;               // first owned float2 index
    #pragma unroll
    for (int u4 = 0; u4 < 4; u4++) {
        float4 q = make_float4(xr[4 * u4], xr[4 * u4 + 1], xr[4 * u4 + 2], xr[4 * u4 + 3]);
        *reinterpret_cast<float4*>(&Z[SW(fb2 + 2 * u4)]) = q;
    }
    #pragma unroll
    for (int o = 32; o > 0; o >>= 1) {
        s += __shfl_down(s, o);
        mn = fminf(mn, __shfl_down(mn, o));
        mx = fmaxf(mx, __shfl_down(mx, o));
    }
    const int lane = tid & 63, wv = tid >> 6;
    if (lane == 0) {
        scr[SCR_A_PART + wv * 3 + 0] = s;
        scr[SCR_A_PART + wv * 3 + 1] = mn;
        scr[SCR_A_PART + wv * 3 + 2] = mx;
    }
    __syncthreads();                                     // sync 1

    // boundary x[16t-6..16t-1] raw reads hoisted here: data valid after sync 1,
    // latency overlaps the A-finalize + sync 2 wait (subtract m deferred).
    float2 tv = make_float2(0.f, 0.f);
    float4 tq = make_float4(0.f, 0.f, 0.f, 0.f);
    if (tid > 0) {
        tv = Z[SW(fb2 - 3)];
        tq = *reinterpret_cast<const float4*>(&Z[SW(fb2 - 2)]);
    }
    if (tid < 3) {
        float r = scr[SCR_A_PART + tid];
        #pragma unroll
        for (int w = 1; w < NWAVES; w++) {
            float vv = scr[SCR_A_PART + w * 3 + tid];
            r = (tid == 0) ? (r + vv) : ((tid == 1) ? fminf(r, vv) : fmaxf(r, vv));
        }
        scr[SCR_A_FIN + tid] = r;
    }
    __syncthreads();                                     // sync 2
    const float m = scr[SCR_A_FIN + 0] * (1.f / T_LEN);

    // ---------- sweep 2: fused moments/slope/ACF from REGISTERS ----------
    {
        float q2 = 0.f, q3 = 0.f, q4 = 0.f, qt = 0.f;
        float l1 = 0.f, l2 = 0.f, l3 = 0.f, l4 = 0.f, l5 = 0.f, l6 = 0.f;
        float p1v, p2v, p3v, p4v, p5v, p6v;
        if (tid > 0) {
            p6v = tv.x - m; p5v = tv.y - m;
            p4v = tq.x - m; p3v = tq.y - m; p2v = tq.z - m; p1v = tq.w - m;
        } else {
            p1v = p2v = p3v = p4v = p5v = p6v = 0.f;     // reference zero-pads
        }
        const float tf0 = (float)(tid * 16) - 2047.5f;
        #pragma unroll
        for (int u = 0; u < 16; u++) {
            float c = xr[u] - m;
            float cc = c * c;
            q2 += cc; q3 += cc * c; q4 += cc * cc;
            qt += c * (tf0 + (float)u);
            l1 += p1v * c; l2 += p2v * c; l3 += p3v * c;
            l4 += p4v * c; l5 += p5v * c; l6 += p6v * c;
            p6v = p5v; p5v = p4v; p4v = p3v; p3v = p2v; p2v = p1v; p1v = c;
        }
        #pragma unroll
        for (int o = 32; o >= 4; o >>= 1) {
            q2 += __shfl_down(q2, o); q3 += __shfl_down(q3, o);
            q4 += __shfl_down(q4, o); qt += __shfl_down(qt, o);
            l1 += __shfl_down(l1, o); l2 += __shfl_down(l2, o);
            l3 += __shfl_down(l3, o); l4 += __shfl_down(l4, o);
            l5 += __shfl_down(l5, o); l6 += __shfl_down(l6, o);
        }
        if (lane < 4) {
            float* part = &scr[SCR_B_PART + wv * 40 + lane * 10];
            part[0] = q2; part[1] = q3; part[2] = q4; part[3] = qt;
            part[4] = l1; part[5] = l2; part[6] = l3;
            part[7] = l4; part[8] = l5; part[9] = l6;
        }
    }
    __syncthreads();                                     // sync 3

    // ---------- B finalize overlapped with FFT stage 0 ----------
    if (tid < 10) {
        float acc = 0.f;
        #pragma unroll
        for (int e = 0; e < 16; e++) acc += scr[SCR_B_PART + e * 10 + tid];
        scr[SCR_B_FIN + tid] = acc;
    }
    fft_stage<0>(Z, tid);
    __syncthreads();                                     // sync 4

    // feats base features by tid 0 (feature-major), overlap FFT stage 1
    if (tid == 0) {
        const float* A = &scr[SCR_B_FIN];
        float c2 = A[0], c3 = A[1], c4 = A[2], ct = A[3];
        float var = c2 * (1.f / T_LEN);
        float sd  = sqrtf(var + 1e-8f);
        float i3  = 1.f / (sd * sd * sd);
        float dn  = c2 + 1e-8f;
        float* fp = feats + sid;
        fp[0 * FS] = m; fp[1 * FS] = sd;
        fp[2 * FS] = c3 * (1.f / T_LEN) * i3;
        fp[3 * FS] = c4 * (1.f / T_LEN) * i3 / sd;
        fp[4 * FS] = scr[SCR_A_FIN + 1]; fp[5 * FS] = scr[SCR_A_FIN + 2];
        fp[6 * FS] = ct / 5726622720.f;                  // sum(tc^2) = T(T^2-1)/12
        fp[10 * FS] = A[4] / dn; fp[11 * FS] = A[5] / dn; fp[12 * FS] = A[6] / dn;
        fp[13 * FS] = A[7] / dn; fp[14 * FS] = A[8] / dn; fp[15 * FS] = A[9] / dn;
    }
    fft_stage<1>(Z, tid);
    __syncthreads();                                     // sync 5
    fft_stage<2>(Z, tid);
    __syncthreads();                                     // sync 6
    fft_stage<3>(Z, tid);
    __syncthreads();                                     // sync 7
    fft_stage<4>(Z, tid);
    __syncthreads();                                     // sync 8

    // ---------- magnitudes: conjugate pair once; mag^2, sqrt deferred ----------
    // X_k = (Er+u, Ei+v), X_{2048-k} = (Er-u, v-Ei)
    const float inv_T = 1.f / (float)T_LEN;
    float a0 = -1.f, a1 = -1.f, a2 = -1.f;               // top-3 of |X|^2
    #pragma unroll
    for (int i = 0; i < 4; i++) {
        int k  = 1 + tid + (i << 8);                     // 1..1024
        int pa = fpos(k);
        int pb = fpos(M_LEN - k);
        float ang = (float)k * (-3.14159265358979f / (float)M_LEN);
        float sn, cs; __sincosf(ang, &sn, &cs);
        float2 Za = rdpost(Z, pa), Zb = rdpost(Z, pb);
        float Er = 0.5f * (Za.x + Zb.x), Ei = 0.5f * (Za.y - Zb.y);
        float Or = 0.5f * (Za.y + Zb.y), Oi = 0.5f * (Zb.x - Za.x);
        float u = cs * Or - sn * Oi, vv = cs * Oi + sn * Or;
        float Xr = Er + u, Xi = Ei + vv;
        ins3(a0, a1, a2, Xr * Xr + Xi * Xi);
        if (k != 1024) {
            float Yr = Er - u, Yi = vv - Ei;
            ins3(a0, a1, a2, Yr * Yr + Yi * Yi);
        }
    }
    if (tid == 0) {                                      // Nyquist k=2048
        float2 Z0 = rdpost(Z, 0);
        float d = Z0.x - Z0.y;
        ins3(a0, a1, a2, d * d);
    }
    #pragma unroll
    for (int o = 32; o > 0; o >>= 1) {
        float u0 = __shfl_down(a0, o), u1 = __shfl_down(a1, o), u2 = __shfl_down(a2, o);
        ins3(a0, a1, a2, u0); ins3(a0, a1, a2, u1); ins3(a0, a1, a2, u2);
    }
    if (lane == 0) {
        scr[SCR_C_PART + wv * 3 + 0] = a0;
        scr[SCR_C_PART + wv * 3 + 1] = a1;
        scr[SCR_C_PART + wv * 3 + 2] = a2;
    }
    __syncthreads();                                     // sync 9
    if (tid == 0) {
        float t0 = scr[SCR_C_PART], t1 = scr[SCR_C_PART + 1], t2 = scr[SCR_C_PART + 2];
        #pragma unroll
        for (int w = 1; w < NWAVES; w++) {
            ins3(t0, t1, t2, scr[SCR_C_PART + w * 3 + 0]);
            ins3(t0, t1, t2, scr[SCR_C_PART + w * 3 + 1]);
            ins3(t0, t1, t2, scr[SCR_C_PART + w * 3 + 2]);
        }
        float* fp = feats + sid;
        fp[7 * FS] = sqrtf(t0) * inv_T;
        fp[8 * FS] = sqrtf(t1) * inv_T;
        fp[9 * FS] = sqrtf(t2) * inv_T;
    }
}

// One 32-lane group per (b, f): coalesced 128-B read + shuffle reduce.
__global__ __launch_bounds__(256)
void ts_reduce_kernel(const float* __restrict__ feats, float* __restrict__ out) {
    const int tid = threadIdx.x;
    const int lane = tid & 63;
    const int wid = blockIdx.x * 4 + (tid >> 6);      // global wave 0..1023
    const int pairidx = wid * 2 + (lane >> 5);        // (b,f) pair 0..2047
    const int b = pairidx >> 4, f = pairidx & 15;
    const int v = lane & 31;
    float val = feats[f * FS + b * V_DIM + v];
    float s = val;
    #pragma unroll
    for (int o = 16; o > 0; o >>= 1) s += __shfl_xor(s, o);
    float m = s * (1.f / V_DIM);
    float d = val - m;
    float q = d * d;
    #pragma unroll
    for (int o = 16; o > 0; o >>= 1) q += __shfl_xor(q, o);
    float sd = sqrtf(q * (1.f / V_DIM));
    if (v == 0) {
        out[b * 32 + f]      = fminf(fmaxf(m,  -5.f), 5.f);
        out[b * 32 + 16 + f] = fminf(fmaxf(sd, -5.f), 5.f);
    }
}

extern "C" void kernel_launch(void* const* d_in, const int* in_sizes, int n_in,
                              void* d_out, int out_size, void* d_ws, size_t ws_size,
                              hipStream_t stream) {
    const float* x = (const float*)d_in[0];
    float* out = (float*)d_out;
    float* feats = (float*)d_ws;   // feature-major [16][4096] = 256 KB

    hipLaunchKernelGGL(ts_feat_kernel, dim3(NSERIES), dim3(NTHREADS), 0, stream,
                       x, feats);
    hipLaunchKernelGGL(ts_reduce_kernel, dim3(256), dim3(256), 0, stream,
                       feats, out);
}

// Round 25
// 125.769 us; speedup vs baseline: 1.0121x; 1.0102x over previous
//
#include <hip/hip_runtime.h>
#include <math.h>

#define T_LEN 4096
#define M_LEN 2048   // complex length after real-packing
#define V_DIM 32
#define B_DIM 128
#define NTHREADS 256
#define NWAVES 4
#define NSERIES 4096          // B_DIM * V_DIM
#define FS NSERIES            // feats stride: feature-major [f][sid]

// LDS bank swizzle on float2 index: fold addr bits 4-6 into 1-3 AND bits 7-10
// into 1-4 (kills the 16-way magnitude-gather conflict; r23: 5.0e6 -> 1.7e6).
// Bit 0 untouched; XOR terms depend only on bits>=4 -> even/odd f2 pairs stay
// adjacent (b128-safe, 16B aligned); bijective; range-preserving.
__device__ __forceinline__ int SW(int i) {
    return i ^ (((i >> 4) & 7) << 1) ^ (((i >> 7) & 15) << 1);
}

// storage position of frequency k after DIF [radix-4 x5, radix-2] (digit reversal)
__device__ __forceinline__ int fpos(int k) {
    return ((k & 3) << 9) | (((k >> 2) & 3) << 7) | (((k >> 4) & 3) << 5)
         | (((k >> 6) & 3) << 3) | (((k >> 8) & 3) << 1) | ((k >> 10) & 1);
}

// insert m into descending triple (a0 >= a1 >= a2)
__device__ __forceinline__ void ins3(float& a0, float& a1, float& a2, float m) {
    if (m > a0) { a2 = a1; a1 = a0; a0 = m; }
    else if (m > a1) { a2 = a1; a1 = m; }
    else if (m > a2) { a2 = m; }
}

// scr float regions (single series, 4 waves)
#define SCR_A_PART 0     // 4 waves x 3 [sum,mn,mx]
#define SCR_A_FIN  12    // 3
#define SCR_B_PART 16    // 4 waves x 4 lanes x 10
#define SCR_B_FIN  176   // 10
#define SCR_C_PART 186   // 4 waves x 3
#define SCR_SIZE   200

// one radix-4 DIF butterfly at (base, quarter q) with twiddles W^j, W^2j, W^3j
__device__ __forceinline__ void bfly4(float2* Z, int base, int q,
                                      float sn, float cs, float c2, float s2,
                                      float c3, float s3) {
    const int p0 = SW(base), p1 = SW(base + q);
    const int p2i = SW(base + 2 * q), p3 = SW(base + 3 * q);
    float2 a = Z[p0], bb = Z[p1], c = Z[p2i], d = Z[p3];
    float t0r = a.x + c.x,  t0i = a.y + c.y;
    float t1r = a.x - c.x,  t1i = a.y - c.y;
    float t2r = bb.x + d.x, t2i = bb.y + d.y;
    float t3r = bb.x - d.x, t3i = bb.y - d.y;
    float y1r = t1r + t3i, y1i = t1i - t3r;
    float y2r = t0r - t2r, y2i = t0i - t2i;
    float y3r = t1r - t3i, y3i = t1i + t3r;
    Z[p0]  = make_float2(t0r + t2r, t0i + t2i);
    Z[p1]  = make_float2(y1r * cs - y1i * sn, y1r * sn + y1i * cs);
    Z[p2i] = make_float2(y2r * c2 - y2i * s2, y2r * s2 + y2i * c2);
    Z[p3]  = make_float2(y3r * c3 - y3i * s3, y3r * s3 + y3i * c3);
}

// radix-4 DIF stage (ST 0..3), in place, swizzled addressing. W = e^{-2pi i/2048}.
// For ST>=1 the thread's two butterflies share j (256 % q == 0) -> one sincos.
template <int ST>
__device__ __forceinline__ void fft_stage(float2* Z, int tid) {
    constexpr int lq = 9 - 2 * ST;           // log2(quarter)
    constexpr int q  = 1 << lq;
    const float scale = -3.06796158e-3f * (float)(1 << (2 * ST)); // -2pi/2048 * 4^ST
    if constexpr (ST == 0) {
        #pragma unroll
        for (int i = 0; i < 2; i++) {
            const int w = tid + (i << 8);
            const int g = w >> lq;
            const int j = w & (q - 1);
            float sn, cs;
            __sincosf(scale * (float)j, &sn, &cs);
            const float c2 = cs * cs - sn * sn, s2 = 2.f * cs * sn;
            const float c3 = c2 * cs - s2 * sn, s3 = c2 * sn + s2 * cs;
            bfly4(Z, (g << (lq + 2)) + j, q, sn, cs, c2, s2, c3, s3);
        }
    } else {
        const int j = tid & (q - 1);
        float sn, cs;
        __sincosf(scale * (float)j, &sn, &cs);
        const float c2 = cs * cs - sn * sn, s2 = 2.f * cs * sn;
        const float c3 = c2 * cs - s2 * sn, s3 = c2 * sn + s2 * cs;
        #pragma unroll
        for (int i = 0; i < 2; i++) {
            const int g = (tid + (i << 8)) >> lq;
            bfly4(Z, (g << (lq + 2)) + j, q, sn, cs, c2, s2, c3, s3);
        }
    }
}

// merged stage 4 (q=2; twiddles W_8^j are constants) + final radix-2.
// Thread t owns logical block [8t, 8t+8) entirely: 4x b128 in, registers, 4x b128 out.
__device__ __forceinline__ void fft_stage4_r2(float2* Z, int tid) {
    const int base = tid * 8;
    float4 P0 = *reinterpret_cast<const float4*>(&Z[SW(base)]);      // x0,x1
    float4 P2 = *reinterpret_cast<const float4*>(&Z[SW(base + 2)]);  // x2,x3
    float4 P4 = *reinterpret_cast<const float4*>(&Z[SW(base + 4)]);  // x4,x5
    float4 P6 = *reinterpret_cast<const float4*>(&Z[SW(base + 6)]);  // x6,x7
    // j=0 butterfly on x0,x2,x4,x6 (twiddles = 1)
    float t0r = P0.x + P4.x, t0i = P0.y + P4.y;
    float t1r = P0.x - P4.x, t1i = P0.y - P4.y;
    float t2r = P2.x + P6.x, t2i = P2.y + P6.y;
    float t3r = P2.x - P6.x, t3i = P2.y - P6.y;
    float o0r = t0r + t2r, o0i = t0i + t2i;
    float o2r = t1r + t3i, o2i = t1i - t3r;
    float o4r = t0r - t2r, o4i = t0i - t2i;
    float o6r = t1r - t3i, o6i = t1i + t3r;
    // j=1 butterfly on x1,x3,x5,x7; W = e^{-i pi/4}: W=(C,-C), W^2=-i, W^3=(-C,-C)
    const float C = 0.70710678118654752f;
    float u0r = P0.z + P4.z, u0i = P0.w + P4.w;
    float u1r = P0.z - P4.z, u1i = P0.w - P4.w;
    float u2r = P2.z + P6.z, u2i = P2.w + P6.w;
    float u3r = P2.z - P6.z, u3i = P2.w - P6.w;
    float o1r = u0r + u2r, o1i = u0i + u2i;
    float y1r = u1r + u3i, y1i = u1i - u3r;              // t1 - i t3
    float o3r = C * (y1r + y1i), o3i = C * (y1i - y1r);  // * (C,-C)
    float y2r = u0r - u2r, y2i = u0i - u2i;
    float o5r = y2i, o5i = -y2r;                         // * -i
    float y3r = u1r - u3i, y3i = u1i + u3r;              // t1 + i t3
    float o7r = C * (y3i - y3r), o7i = -C * (y3r + y3i); // * (-C,-C)
    // final radix-2 (twiddle-free) on pairs (0,1)(2,3)(4,5)(6,7)
    float4 R0 = make_float4(o0r + o1r, o0i + o1i, o0r - o1r, o0i - o1i);
    float4 R2 = make_float4(o2r + o3r, o2i + o3i, o2r - o3r, o2i - o3i);
    float4 R4 = make_float4(o4r + o5r, o4i + o5i, o4r - o5r, o4i - o5i);
    float4 R6 = make_float4(o6r + o7r, o6i + o7i, o6r - o7r, o6i - o7i);
    *reinterpret_cast<float4*>(&Z[SW(base)])     = R0;
    *reinterpret_cast<float4*>(&Z[SW(base + 2)]) = R2;
    *reinterpret_cast<float4*>(&Z[SW(base + 4)]) = R4;
    *reinterpret_cast<float4*>(&Z[SW(base + 6)]) = R6;
}

__global__ __launch_bounds__(NTHREADS, 8)   // 8 blocks/CU: 32 waves (session-best config)
void ts_feat_kernel(const float* __restrict__ x, float* __restrict__ feats) {
    __shared__ __align__(16) float data[T_LEN];      // 16 KB swizzled packed-complex
    __shared__ float scr[SCR_SIZE];
    float2* const Z = reinterpret_cast<float2*>(&data[0]);

    const int tid = threadIdx.x;
    // XCD swizzle: all 32 v-blocks of batch b land on XCD b&7; bijective over 4096.
    const int bid = blockIdx.x;            // 0..4095
    const int xcd = bid & 7;
    const int idx = bid >> 3;              // 0..511
    const int b   = xcd + ((idx >> 5) << 3);    // batch 0..127
    const int v   = idx & 31;
    const int sid = b * V_DIM + v;

    const float* __restrict__ px = x + (size_t)b * T_LEN * V_DIM + v;

    // ---------- sweep 1: 16 scalar loads -> regs; sum/min/max; LDS store ----------
    float xr[16];
    #pragma unroll
    for (int u = 0; u < 16; u++) {
        xr[u] = px[(size_t)(16 * tid + u) * V_DIM];
    }
    float s = 0.f, mn = 3.4e38f, mx = -3.4e38f;
    #pragma unroll
    for (int u = 0; u < 16; u++) {
        s += xr[u]; mn = fminf(mn, xr[u]); mx = fmaxf(mx, xr[u]);
    }
    const int fb2 = tid * 8;               // first owned float2 index
    #pragma unroll
    for (int u4 = 0; u4 < 4; u4++) {
        float4 q = make_float4(xr[4 * u4], xr[4 * u4 + 1], xr[4 * u4 + 2], xr[4 * u4 + 3]);
        *reinterpret_cast<float4*>(&Z[SW(fb2 + 2 * u4)]) = q;
    }
    #pragma unroll
    for (int o = 32; o > 0; o >>= 1) {
        s += __shfl_down(s, o);
        mn = fminf(mn, __shfl_down(mn, o));
        mx = fmaxf(mx, __shfl_down(mx, o));
    }
    const int lane = tid & 63, wv = tid >> 6;
    if (lane == 0) {
        scr[SCR_A_PART + wv * 3 + 0] = s;
        scr[SCR_A_PART + wv * 3 + 1] = mn;
        scr[SCR_A_PART + wv * 3 + 2] = mx;
    }
    __syncthreads();                                     // sync 1

    // boundary x[16t-6..16t-1] raw reads hoisted: data valid after sync 1,
    // latency overlaps the A-finalize + sync 2 wait (subtract m deferred).
    float2 tv = make_float2(0.f, 0.f);
    float4 tq = make_float4(0.f, 0.f, 0.f, 0.f);
    if (tid > 0) {
        tv = Z[SW(fb2 - 3)];
        tq = *reinterpret_cast<const float4*>(&Z[SW(fb2 - 2)]);
    }
    if (tid < 3) {
        float r = scr[SCR_A_PART + tid];
        #pragma unroll
        for (int w = 1; w < NWAVES; w++) {
            float vv = scr[SCR_A_PART + w * 3 + tid];
            r = (tid == 0) ? (r + vv) : ((tid == 1) ? fminf(r, vv) : fmaxf(r, vv));
        }
        scr[SCR_A_FIN + tid] = r;
    }
    __syncthreads();                                     // sync 2
    const float m = scr[SCR_A_FIN + 0] * (1.f / T_LEN);

    // ---------- sweep 2: fused moments/slope/ACF from REGISTERS ----------
    {
        float q2 = 0.f, q3 = 0.f, q4 = 0.f, qt = 0.f;
        float l1 = 0.f, l2 = 0.f, l3 = 0.f, l4 = 0.f, l5 = 0.f, l6 = 0.f;
        float p1v, p2v, p3v, p4v, p5v, p6v;
        if (tid > 0) {
            p6v = tv.x - m; p5v = tv.y - m;
            p4v = tq.x - m; p3v = tq.y - m; p2v = tq.z - m; p1v = tq.w - m;
        } else {
            p1v = p2v = p3v = p4v = p5v = p6v = 0.f;     // reference zero-pads
        }
        const float tf0 = (float)(tid * 16) - 2047.5f;
        #pragma unroll
        for (int u = 0; u < 16; u++) {
            float c = xr[u] - m;
            float cc = c * c;
            q2 += cc; q3 += cc * c; q4 += cc * cc;
            qt += c * (tf0 + (float)u);
            l1 += p1v * c; l2 += p2v * c; l3 += p3v * c;
            l4 += p4v * c; l5 += p5v * c; l6 += p6v * c;
            p6v = p5v; p5v = p4v; p4v = p3v; p3v = p2v; p2v = p1v; p1v = c;
        }
        #pragma unroll
        for (int o = 32; o >= 4; o >>= 1) {
            q2 += __shfl_down(q2, o); q3 += __shfl_down(q3, o);
            q4 += __shfl_down(q4, o); qt += __shfl_down(qt, o);
            l1 += __shfl_down(l1, o); l2 += __shfl_down(l2, o);
            l3 += __shfl_down(l3, o); l4 += __shfl_down(l4, o);
            l5 += __shfl_down(l5, o); l6 += __shfl_down(l6, o);
        }
        if (lane < 4) {
            float* part = &scr[SCR_B_PART + wv * 40 + lane * 10];
            part[0] = q2; part[1] = q3; part[2] = q4; part[3] = qt;
            part[4] = l1; part[5] = l2; part[6] = l3;
            part[7] = l4; part[8] = l5; part[9] = l6;
        }
    }
    __syncthreads();                                     // sync 3

    // ---------- B finalize overlapped with FFT stage 0 ----------
    if (tid < 10) {
        float acc = 0.f;
        #pragma unroll
        for (int e = 0; e < 16; e++) acc += scr[SCR_B_PART + e * 10 + tid];
        scr[SCR_B_FIN + tid] = acc;
    }
    fft_stage<0>(Z, tid);
    __syncthreads();                                     // sync 4

    // feats base features by tid 0 (feature-major), overlap FFT stage 1
    if (tid == 0) {
        const float* A = &scr[SCR_B_FIN];
        float c2 = A[0], c3 = A[1], c4 = A[2], ct = A[3];
        float var = c2 * (1.f / T_LEN);
        float sd  = sqrtf(var + 1e-8f);
        float i3  = 1.f / (sd * sd * sd);
        float dn  = c2 + 1e-8f;
        float* fp = feats + sid;
        fp[0 * FS] = m; fp[1 * FS] = sd;
        fp[2 * FS] = c3 * (1.f / T_LEN) * i3;
        fp[3 * FS] = c4 * (1.f / T_LEN) * i3 / sd;
        fp[4 * FS] = scr[SCR_A_FIN + 1]; fp[5 * FS] = scr[SCR_A_FIN + 2];
        fp[6 * FS] = ct / 5726622720.f;                  // sum(tc^2) = T(T^2-1)/12
        fp[10 * FS] = A[4] / dn; fp[11 * FS] = A[5] / dn; fp[12 * FS] = A[6] / dn;
        fp[13 * FS] = A[7] / dn; fp[14 * FS] = A[8] / dn; fp[15 * FS] = A[9] / dn;
    }
    fft_stage<1>(Z, tid);
    __syncthreads();                                     // sync 5
    fft_stage<2>(Z, tid);
    __syncthreads();                                     // sync 6
    fft_stage<3>(Z, tid);
    __syncthreads();                                     // sync 7
    fft_stage4_r2(Z, tid);                               // thread-local: no extra barrier
    __syncthreads();                                     // sync 8

    // ---------- magnitudes: conjugate pair once; mag^2, sqrt deferred ----------
    // radix-2 already applied in LDS -> plain float2 reads.
    // X_k = (Er+u, Ei+v), X_{2048-k} = (Er-u, v-Ei)
    const float inv_T = 1.f / (float)T_LEN;
    float a0 = -1.f, a1 = -1.f, a2 = -1.f;               // top-3 of |X|^2
    #pragma unroll
    for (int i = 0; i < 4; i++) {
        int k  = 1 + tid + (i << 8);                     // 1..1024
        int pa = fpos(k);
        int pb = fpos(M_LEN - k);
        float ang = (float)k * (-3.14159265358979f / (float)M_LEN);
        float sn, cs; __sincosf(ang, &sn, &cs);
        float2 Za = Z[SW(pa)], Zb = Z[SW(pb)];
        float Er = 0.5f * (Za.x + Zb.x), Ei = 0.5f * (Za.y - Zb.y);
        float Or = 0.5f * (Za.y + Zb.y), Oi = 0.5f * (Zb.x - Za.x);
        float u = cs * Or - sn * Oi, vv = cs * Oi + sn * Or;
        float Xr = Er + u, Xi = Ei + vv;
        ins3(a0, a1, a2, Xr * Xr + Xi * Xi);
        if (k != 1024) {
            float Yr = Er - u, Yi = vv - Ei;
            ins3(a0, a1, a2, Yr * Yr + Yi * Yi);
        }
    }
    if (tid == 0) {                                      // Nyquist k=2048
        float2 Z0 = Z[SW(0)];
        float d = Z0.x - Z0.y;
        ins3(a0, a1, a2, d * d);
    }
    #pragma unroll
    for (int o = 32; o > 0; o >>= 1) {
        float u0 = __shfl_down(a0, o), u1 = __shfl_down(a1, o), u2 = __shfl_down(a2, o);
        ins3(a0, a1, a2, u0); ins3(a0, a1, a2, u1); ins3(a0, a1, a2, u2);
    }
    if (lane == 0) {
        scr[SCR_C_PART + wv * 3 + 0] = a0;
        scr[SCR_C_PART + wv * 3 + 1] = a1;
        scr[SCR_C_PART + wv * 3 + 2] = a2;
    }
    __syncthreads();                                     // sync 9
    if (tid == 0) {
        float t0 = scr[SCR_C_PART], t1 = scr[SCR_C_PART + 1], t2 = scr[SCR_C_PART + 2];
        #pragma unroll
        for (int w = 1; w < NWAVES; w++) {
            ins3(t0, t1, t2, scr[SCR_C_PART + w * 3 + 0]);
            ins3(t0, t1, t2, scr[SCR_C_PART + w * 3 + 1]);
            ins3(t0, t1, t2, scr[SCR_C_PART + w * 3 + 2]);
        }
        float* fp = feats + sid;
        fp[7 * FS] = sqrtf(t0) * inv_T;
        fp[8 * FS] = sqrtf(t1) * inv_T;
        fp[9 * FS] = sqrtf(t2) * inv_T;
    }
}

// One 32-lane group per (b, f): coalesced 128-B read + shuffle reduce.
__global__ __launch_bounds__(256)
void ts_reduce_kernel(const float* __restrict__ feats, float* __restrict__ out) {
    const int tid = threadIdx.x;
    const int lane = tid & 63;
    const int wid = blockIdx.x * 4 + (tid >> 6);      // global wave 0..1023
    const int pairidx = wid * 2 + (lane >> 5);        // (b,f) pair 0..2047
    const int b = pairidx >> 4, f = pairidx & 15;
    const int v = lane & 31;
    float val = feats[f * FS + b * V_DIM + v];
    float s = val;
    #pragma unroll
    for (int o = 16; o > 0; o >>= 1) s += __shfl_xor(s, o);
    float m = s * (1.f / V_DIM);
    float d = val - m;
    float q = d * d;
    #pragma unroll
    for (int o = 16; o > 0; o >>= 1) q += __shfl_xor(q, o);
    float sd = sqrtf(q * (1.f / V_DIM));
    if (v == 0) {
        out[b * 32 + f]      = fminf(fmaxf(m,  -5.f), 5.f);
        out[b * 32 + 16 + f] = fminf(fmaxf(sd, -5.f), 5.f);
    }
}

extern "C" void kernel_launch(void* const* d_in, const int* in_sizes, int n_in,
                              void* d_out, int out_size, void* d_ws, size_t ws_size,
                              hipStream_t stream) {
    const float* x = (const float*)d_in[0];
    float* out = (float*)d_out;
    float* feats = (float*)d_ws;   // feature-major [16][4096] = 256 KB

    hipLaunchKernelGGL(ts_feat_kernel, dim3(NSERIES), dim3(NTHREADS), 0, stream,
                       x, feats);
    hipLaunchKernelGGL(ts_reduce_kernel, dim3(256), dim3(256), 0, stream,
                       feats, out);
}